// Round 3
// baseline (191.942 us; speedup 1.0000x reference)
//
#include <hip/hip_runtime.h>

// AdderNet conv: out[n,co,i,j] = -sum_{ci,kh,kw} |x[n,ci,i+kh,j+kw] - W[co,ci,kh,kw]|
// x: (16,5,512,512) fp32, W: (5,5,3,3) fp32, out: (16,5,510,510) fp32
//
// R3: __launch_bounds__(256,4) -> 128-VGPR budget (R2's silent 40-VGPR squeeze
// caused re-materialization). 2 rows x 4 cols x 5 co = 40 outputs/thread;
// window loaded as float4+float2 per row (1 load instr per output value).

#define KK 3
#define NB 16
#define CI 5
#define CO 5
#define H 512
#define WD 512
#define HO 510
#define WO 510
#define TW 256  // cols per block = 64 lanes x 4
#define TH 8    // rows per block = 4 ty x 2

__global__ __launch_bounds__(256, 4)
void adder2d_kernel(const float* __restrict__ x,
                    const float* __restrict__ Wg,
                    float* __restrict__ out) {
    const int tx = threadIdx.x & 63;
    const int ty = threadIdx.x >> 6;
    const int j0 = blockIdx.x * TW;       // 0 or 256
    const int i0 = blockIdx.y * TH;
    const int n  = blockIdx.z;

    const int j     = j0 + tx * 4;        // first of 4 output cols (always %4==0, <=508)
    const int ibase = i0 + ty * 2;        // first of 2 output rows

    // Row offsets for the 4 window rows (clamped; clamped rows only feed invalid outputs)
    int rowoff[4];
    #pragma unroll
    for (int r = 0; r < 4; ++r) {
        int gi = ibase + r;
        gi = gi < H ? gi : (H - 1);
        rowoff[r] = gi * WD;
    }
    // Second (float2) load covers cols j+4, j+5; clamp base so it stays in-bounds.
    // Clamped values only feed output cols >= 510, which are predicated off.
    const int j2 = (j + 4 <= WD - 2) ? (j + 4) : (WD - 2);

    const float* xn = x + (size_t)n * CI * H * WD;

    float acc[CO][2][4];
    #pragma unroll
    for (int co = 0; co < CO; ++co)
        #pragma unroll
        for (int r = 0; r < 2; ++r)
            #pragma unroll
            for (int c = 0; c < 4; ++c) acc[co][r][c] = 0.f;

    #pragma unroll 1
    for (int ci = 0; ci < CI; ++ci) {
        const float* p = xn + (size_t)ci * H * WD;
        // 4-row x 6-col window: float4 + float2 per row
        float win[4][6];
        #pragma unroll
        for (int r = 0; r < 4; ++r) {
            const float* rp = p + rowoff[r];
            const float4 a = *(const float4*)(rp + j);
            const float2 b = *(const float2*)(rp + j2);
            win[r][0] = a.x; win[r][1] = a.y; win[r][2] = a.z; win[r][3] = a.w;
            win[r][4] = b.x; win[r][5] = b.y;
        }
        const float* wp = Wg + ci * (KK * KK);   // W[co][ci][kh][kw], co stride 45
        #pragma unroll
        for (int kh = 0; kh < KK; ++kh) {
            #pragma unroll
            for (int kw = 0; kw < KK; ++kw) {
                const int widx = kh * KK + kw;
                const float w0 = wp[0 * 45 + widx];
                const float w1 = wp[1 * 45 + widx];
                const float w2 = wp[2 * 45 + widx];
                const float w3 = wp[3 * 45 + widx];
                const float w4 = wp[4 * 45 + widx];
                #pragma unroll
                for (int r = 0; r < 2; ++r) {
                    #pragma unroll
                    for (int c = 0; c < 4; ++c) {
                        const float xv = win[kh + r][kw + c];
                        acc[0][r][c] += fabsf(xv - w0);
                        acc[1][r][c] += fabsf(xv - w1);
                        acc[2][r][c] += fabsf(xv - w2);
                        acc[3][r][c] += fabsf(xv - w3);
                        acc[4][r][c] += fabsf(xv - w4);
                    }
                }
            }
        }
    }

    // Stores: float2 pairs. Low pair (cols j,j+1) always valid (j<=508).
    // High pair (cols j+2,j+3) valid iff j+3 < WO.
    const bool hi_ok = (j + 3) < WO;
    float* outn = out + (size_t)n * CO * HO * WO;
    #pragma unroll
    for (int co = 0; co < CO; ++co) {
        float* outc = outn + (size_t)co * HO * WO;
        #pragma unroll
        for (int r = 0; r < 2; ++r) {
            const int i = ibase + r;
            if (i < HO) {
                float* op = outc + (size_t)i * WO + j;
                *(float2*)(op)     = make_float2(-acc[co][r][0], -acc[co][r][1]);
                if (hi_ok)
                    *(float2*)(op + 2) = make_float2(-acc[co][r][2], -acc[co][r][3]);
            }
        }
    }
}

extern "C" void kernel_launch(void* const* d_in, const int* in_sizes, int n_in,
                              void* d_out, int out_size, void* d_ws, size_t ws_size,
                              hipStream_t stream) {
    const float* x  = (const float*)d_in[0];
    const float* Wg = (const float*)d_in[1];
    float* out      = (float*)d_out;

    dim3 grid((WO + TW - 1) / TW,   // 2
              (HO + TH - 1) / TH,   // 64
              NB);                  // 16
    dim3 block(256);
    adder2d_kernel<<<grid, block, 0, stream>>>(x, Wg, out);
}